// Round 7
// baseline (686.148 us; speedup 1.0000x reference)
//
#include <hip/hip_runtime.h>
#include <hip/hip_bf16.h>
#include <math.h>

#define N 8192
#define ZD 128
#define NTILE 64            // N / 128
#define NUPPER 2080         // NTILE*(NTILE+1)/2  (= 8 * 260, divisible by 8)

typedef __attribute__((ext_vector_type(8))) _Float16 f16x8;
typedef __attribute__((ext_vector_type(4))) float f32x4;
typedef __attribute__((ext_vector_type(4))) unsigned int u32x4;

__device__ __forceinline__ int tri_cum(int ti) {   // tiles before row ti
    return (ti * (2 * NTILE + 1 - ti)) / 2;        // ti*(129-ti)/2
}

__device__ __forceinline__ void tile_decode(int t, int& ti, int& tj) {
    int est = (int)((129.0f - sqrtf(16641.0f - 8.0f * (float)t)) * 0.5f);
    if (est < 0) est = 0;
    while (tri_cum(est) > t) --est;
    while (tri_cum(est + 1) <= t) ++est;
    ti = est;
    tj = est + (t - tri_cum(est));
}

// ---------------------------------------------------------------------------
// k1: Z = relu(h @ W1 + b1) @ W2 + b2 (fp32 math), stored as f16.
// Also initializes sums[i] = 1.0 (the fill_diagonal(1) contribution).
// ---------------------------------------------------------------------------
__global__ __launch_bounds__(256) void k1_mlp(
    const float* __restrict__ h, const float* __restrict__ W1,
    const float* __restrict__ b1, const float* __restrict__ W2,
    const float* __restrict__ b2, _Float16* __restrict__ Zf,
    float* __restrict__ sums)
{
    __shared__ float W1s[64][65];
    __shared__ float W2s[64][129];
    __shared__ float hs[32][68];
    __shared__ float Ts[32][68];
    __shared__ float b1s[64];
    __shared__ float b2s[128];
    const int tid = threadIdx.x;
    const int row0 = blockIdx.x * 32;

    if (tid < 32) sums[row0 + tid] = 1.0f;

    for (int e = tid; e < 64 * 64; e += 256) W1s[e >> 6][e & 63] = W1[e];
    for (int e = tid; e < 64 * 128; e += 256) W2s[e >> 7][e & 127] = W2[e];
    for (int e = tid; e < 32 * 64; e += 256) hs[e >> 6][e & 63] = h[(size_t)row0 * 64 + e];
    if (tid < 64) b1s[tid] = b1[tid];
    if (tid < 128) b2s[tid] = b2[tid];
    __syncthreads();

    {
        const int c = tid & 63;
        const int r0 = (tid >> 6) * 8;
        float s[8];
        #pragma unroll
        for (int j = 0; j < 8; ++j) s[j] = b1s[c];
        #pragma unroll
        for (int k0 = 0; k0 < 64; k0 += 4) {
            const float w0 = W1s[k0 + 0][c], w1 = W1s[k0 + 1][c];
            const float w2 = W1s[k0 + 2][c], w3 = W1s[k0 + 3][c];
            #pragma unroll
            for (int j = 0; j < 8; ++j) {
                f32x4 hv = *(const f32x4*)&hs[r0 + j][k0];
                s[j] = fmaf(hv[0], w0, s[j]);
                s[j] = fmaf(hv[1], w1, s[j]);
                s[j] = fmaf(hv[2], w2, s[j]);
                s[j] = fmaf(hv[3], w3, s[j]);
            }
        }
        #pragma unroll
        for (int j = 0; j < 8; ++j) Ts[r0 + j][c] = fmaxf(s[j], 0.0f);
    }
    __syncthreads();
    {
        const int c = tid & 127;
        const int r0 = (tid >> 7) * 16;
        float s[16];
        #pragma unroll
        for (int j = 0; j < 16; ++j) s[j] = b2s[c];
        #pragma unroll
        for (int k0 = 0; k0 < 64; k0 += 4) {
            const float w0 = W2s[k0 + 0][c], w1 = W2s[k0 + 1][c];
            const float w2 = W2s[k0 + 2][c], w3 = W2s[k0 + 3][c];
            #pragma unroll
            for (int j = 0; j < 16; ++j) {
                f32x4 tv = *(const f32x4*)&Ts[r0 + j][k0];
                s[j] = fmaf(tv[0], w0, s[j]);
                s[j] = fmaf(tv[1], w1, s[j]);
                s[j] = fmaf(tv[2], w2, s[j]);
                s[j] = fmaf(tv[3], w3, s[j]);
            }
        }
        #pragma unroll
        for (int j = 0; j < 16; ++j)
            Zf[(size_t)(row0 + r0 + j) * ZD + c] = (_Float16)s[j];
    }
}

// ---------------------------------------------------------------------------
// k3: 2080 upper tiles, XCD-swizzled 1-D grid, 128x128 per block, 4 waves.
// A/B staged ONCE into padded LDS (guaranteed single global read of Zf),
// f16 MFMA GEMM from LDS. Epilogue: LDS T (aliased over A-stage) -> nt-writes
// of logits [i,j] and [j,i]; v = sigmoid(gumbel+L) as u8 into the full
// symmetric vfull matrix (transposed side via vT LDS aliased over B-stage);
// row/col sums in fp32.
// ---------------------------------------------------------------------------
#define AROW 136   // f16 per LDS row (128 + 8 pad)

__global__ __launch_bounds__(256, 2) void k3_main(
    const _Float16* __restrict__ Zf, const float* __restrict__ noise,
    float* __restrict__ logits, unsigned char* __restrict__ vfull,
    float* __restrict__ sums)
{
    int ti, tj;
    const int t = (blockIdx.x & 7) * (NUPPER / 8) + (blockIdx.x >> 3);  // XCD swizzle
    tile_decode(t, ti, tj);
    const bool diag = (ti == tj);

    __shared__ _Float16 smem[2 * 128 * AROW];   // 69632 B
    __shared__ float rs[128], cs[128];
    _Float16* As = smem;                         // [128][AROW]
    _Float16* Bs = smem + 128 * AROW;
    float (*T)[65] = (float(*)[65])smem;         // alias: 33280 B < 34816 (A region)
    unsigned char* vT = (unsigned char*)(smem + 128 * AROW);  // alias: 8 KB in B region

    const int tid = threadIdx.x;
    const int lane = tid & 63;
    const int w = tid >> 6;
    const int wr = w >> 1, wc = w & 1;
    const int fr = lane & 15;     // fragment row
    const int kg = lane >> 4;     // k-group 0..3
    const int i0 = ti * 128, j0 = tj * 128;

    // ---- stage A,B tiles into LDS (single global read of Zf per block) ----
    #pragma unroll
    for (int p = 0; p < 8; ++p) {
        const int c = tid + p * 256;            // 0..2047 chunks of 8 f16
        const int row = c >> 4, cg = (c & 15) << 3;
        *(f16x8*)&As[row * AROW + cg] = *(const f16x8*)(Zf + (size_t)(i0 + row) * ZD + cg);
        *(f16x8*)&Bs[row * AROW + cg] = *(const f16x8*)(Zf + (size_t)(j0 + row) * ZD + cg);
    }
    if (tid < 128) { rs[tid] = 0.0f; cs[tid] = 0.0f; }
    __syncthreads();

    f32x4 acc[4][4];
    #pragma unroll
    for (int mf = 0; mf < 4; ++mf)
        #pragma unroll
        for (int nf = 0; nf < 4; ++nf)
            acc[mf][nf] = (f32x4)0.0f;

    #pragma unroll
    for (int kc = 0; kc < 4; ++kc) {
        const int ko = kc * 32 + kg * 8;
        f16x8 a[4], b[4];
        #pragma unroll
        for (int mf = 0; mf < 4; ++mf) {
            a[mf] = *(const f16x8*)&As[(wr * 64 + mf * 16 + fr) * AROW + ko];
            b[mf] = *(const f16x8*)&Bs[(wc * 64 + mf * 16 + fr) * AROW + ko];
        }
        #pragma unroll
        for (int mf = 0; mf < 4; ++mf)
            #pragma unroll
            for (int nf = 0; nf < 4; ++nf)
                acc[mf][nf] = __builtin_amdgcn_mfma_f32_16x16x32_f16(a[mf], b[nf], acc[mf][nf], 0, 0, 0);
    }

    // ---- epilogue in two 64-column halves ----
    const int c4 = (tid & 15) * 4;        // local col group within half
    const int rbase = tid >> 4;           // 0..15

    #pragma unroll
    for (int half = 0; half < 2; ++half) {
        __syncthreads();   // K-loop (or prev half) done; safe to overwrite aliases
        if (wc == half) {
            #pragma unroll
            for (int mf = 0; mf < 4; ++mf)
                #pragma unroll
                for (int nf = 0; nf < 4; ++nf)
                    #pragma unroll
                    for (int r = 0; r < 4; ++r)
                        T[wr * 64 + mf * 16 + (lane >> 4) * 4 + r][nf * 16 + fr] = acc[mf][nf][r];
        }
        __syncthreads();

        f32x4 csum = (f32x4)0.0f;
        #pragma unroll
        for (int it = 0; it < 8; ++it) {
            const int r = rbase + it * 16;
            f32x4 L4 = *(const f32x4*)&T[r][c4];
            const int lc0 = half * 64 + c4;
            const size_t g = (size_t)(i0 + r) * N + j0 + lc0;
            __builtin_nontemporal_store(L4, (f32x4*)&logits[g]);
            f32x4 u4 = __builtin_nontemporal_load((const f32x4*)&noise[g]);
            float rsum = 0.0f;
            unsigned q = 0;
            #pragma unroll
            for (int e = 0; e < 4; ++e) {
                float u = u4[e];
                float eps = fmaf(-0.9998f, u, 0.9999f);   // eps in [1e-4, 1-1e-4]
                float om  = fmaf( 0.9998f, u, 0.0001f);   // 1 - eps
                float gate = __logf(eps) - __logf(om) + L4[e];
                float v = 1.0f / (1.0f + __expf(-gate));
                if (diag && r >= lc0 + e) v = 0.0f;       // strict upper
                q |= ((unsigned)(int)rintf(v * 255.0f)) << (8 * e);
                rsum += v;
                csum[e] += v;
            }
            if (!diag) {
                __builtin_nontemporal_store(q, (unsigned*)&vfull[g]);
            } else {
                // strictly-upper bytes only (disjoint from transposed writes)
                #pragma unroll
                for (int e = 0; e < 4; ++e)
                    if (r < lc0 + e) vfull[g + e] = (unsigned char)((q >> (8 * e)) & 255);
            }
            // transposed u8 into vT[c][r]
            #pragma unroll
            for (int e = 0; e < 4; ++e)
                vT[(c4 + e) * 128 + r] = (unsigned char)((q >> (8 * e)) & 255);
            atomicAdd(&rs[r], rsum);
        }
        #pragma unroll
        for (int e = 0; e < 4; ++e)
            atomicAdd(&cs[half * 64 + c4 + e], csum[e]);

        __syncthreads();   // vT complete

        // mirrors: logits [j,i] from T, vfull [j,i] from vT
        #pragma unroll
        for (int it = 0; it < 8; ++it) {
            const int idx = tid + it * 256;     // 0..2047
            const int c = idx >> 5;             // 0..63 (col within half)
            const int m4 = (idx & 31) * 4;      // row group
            const unsigned qd = *(const unsigned*)&vT[c * 128 + m4];
            if (!diag) {
                f32x4 o;
                o[0] = T[m4 + 0][c]; o[1] = T[m4 + 1][c];
                o[2] = T[m4 + 2][c]; o[3] = T[m4 + 3][c];
                __builtin_nontemporal_store(o, (f32x4*)&logits[(size_t)(j0 + half * 64 + c) * N + i0 + m4]);
                __builtin_nontemporal_store(qd, (unsigned*)&vfull[(size_t)(j0 + half * 64 + c) * N + i0 + m4]);
            } else {
                const int rr = half * 64 + c;   // local row on the mirrored side
                #pragma unroll
                for (int e = 0; e < 4; ++e)
                    if (m4 + e < rr)
                        vfull[(size_t)(i0 + rr) * N + i0 + m4 + e] = (unsigned char)((qd >> (8 * e)) & 255);
            }
        }
    }

    __syncthreads();
    if (tid < 128) {
        if (diag) {
            atomicAdd(&sums[i0 + tid], rs[tid] + cs[tid]);
        } else {
            atomicAdd(&sums[i0 + tid], rs[tid]);
            atomicAdd(&sums[j0 + tid], cs[tid]);
        }
    }
}

// ---------------------------------------------------------------------------
// k4: d = rsqrt(rowsum)
// ---------------------------------------------------------------------------
__global__ void k4_dvec(const float* __restrict__ sums, float* __restrict__ dvec)
{
    int i = blockIdx.x * 256 + threadIdx.x;
    if (i < N) dvec[i] = rsqrtf(sums[i]);
}

// ---------------------------------------------------------------------------
// k5: pure row-streaming: adj[i,j] = vfull[i,j]/255 * d_i * d_j; diagonal
// element replaced by d_i^2 inline. Sequential u8 reads + f32 writes.
// dvec staged in LDS (32 KB) per block.
// ---------------------------------------------------------------------------
__global__ __launch_bounds__(256) void k5_norm(
    const unsigned char* __restrict__ vfull, float* __restrict__ adj,
    const float* __restrict__ dvec)
{
    __shared__ float dc[N];
    const int tid = threadIdx.x;
    #pragma unroll
    for (int p = 0; p < 8; ++p) {
        const int e = (tid + p * 256) * 4;
        *(f32x4*)&dc[e] = *(const f32x4*)&dvec[e];
    }
    __syncthreads();

    const int row = blockIdx.x * 8 + (tid >> 5);
    const float di = dc[row];
    const float sdi = di * (1.0f / 255.0f);
    const size_t rowbase = (size_t)row * N;
    const int lane32 = tid & 31;

    for (int it = 0; it < 16; ++it) {
        const int j = (lane32 + it * 32) * 16;
        u32x4 qv = __builtin_nontemporal_load((const u32x4*)&vfull[rowbase + j]);
        const bool hasdiag = ((unsigned)(row - j) < 16u);
        #pragma unroll
        for (int k = 0; k < 4; ++k) {
            f32x4 dk = *(const f32x4*)&dc[j + 4 * k];
            const unsigned qd = qv[k];
            f32x4 o;
            o[0] = (float)(qd & 255)         * sdi * dk[0];
            o[1] = (float)((qd >> 8) & 255)  * sdi * dk[1];
            o[2] = (float)((qd >> 16) & 255) * sdi * dk[2];
            o[3] = (float)(qd >> 24)         * sdi * dk[3];
            if (hasdiag) {
                #pragma unroll
                for (int e = 0; e < 4; ++e)
                    if (j + 4 * k + e == row) o[e] = di * di;
            }
            __builtin_nontemporal_store(o, (f32x4*)&adj[rowbase + j + 4 * k]);
        }
    }
}

// ---------------------------------------------------------------------------
extern "C" void kernel_launch(void* const* d_in, const int* in_sizes, int n_in,
                              void* d_out, int out_size, void* d_ws, size_t ws_size,
                              hipStream_t stream)
{
    const float* h     = (const float*)d_in[0];
    const float* W1    = (const float*)d_in[1];
    const float* b1    = (const float*)d_in[2];
    const float* W2    = (const float*)d_in[3];
    const float* b2    = (const float*)d_in[4];
    const float* noise = (const float*)d_in[5];

    float* adj    = (float*)d_out;                 // output 0: adj_norm [N,N]
    float* logits = adj + (size_t)N * N;           // output 1: adj_logits [N,N]

    _Float16* Zf         = (_Float16*)d_ws;                        // 2 MiB
    unsigned char* vfull = (unsigned char*)(Zf + (size_t)N * ZD);  // [N,N] u8 = 64 MiB
    float* sums          = (float*)(vfull + (size_t)N * N);        // [N]
    float* dvec          = sums + N;                               // [N]

    k1_mlp<<<256, 256, 0, stream>>>(h, W1, b1, W2, b2, Zf, sums);
    k3_main<<<NUPPER, 256, 0, stream>>>(Zf, noise, logits, vfull, sums);
    k4_dvec<<<32, 256, 0, stream>>>(sums, dvec);
    k5_norm<<<N / 8, 256, 0, stream>>>(vfull, adj, dvec);
}

// Round 8
// 266.471 us; speedup vs baseline: 2.5749x; 2.5749x over previous
//
#include <hip/hip_runtime.h>
#include <hip/hip_bf16.h>
#include <math.h>

#define N 8192
#define ZD 128
#define NTILE 64            // N / 128
#define NUPPER 2080         // NTILE*(NTILE+1)/2  (= 8 * 260, divisible by 8)

typedef __attribute__((ext_vector_type(8))) _Float16 f16x8;
typedef __attribute__((ext_vector_type(4))) float f32x4;

__device__ __forceinline__ int tri_cum(int ti) {   // tiles before row ti
    return (ti * (2 * NTILE + 1 - ti)) / 2;        // ti*(129-ti)/2
}

__device__ __forceinline__ void tile_decode(int t, int& ti, int& tj) {
    int est = (int)((129.0f - sqrtf(16641.0f - 8.0f * (float)t)) * 0.5f);
    if (est < 0) est = 0;
    while (tri_cum(est) > t) --est;
    while (tri_cum(est + 1) <= t) ++est;
    ti = est;
    tj = est + (t - tri_cum(est));
}

// ---------------------------------------------------------------------------
// k1: Z = relu(h @ W1 + b1) @ W2 + b2 (fp32 math), stored as f16.
// Also initializes sums[i] = 1.0 (the fill_diagonal(1) contribution).
// ---------------------------------------------------------------------------
__global__ __launch_bounds__(256) void k1_mlp(
    const float* __restrict__ h, const float* __restrict__ W1,
    const float* __restrict__ b1, const float* __restrict__ W2,
    const float* __restrict__ b2, _Float16* __restrict__ Zf,
    float* __restrict__ sums)
{
    __shared__ float W1s[64][65];
    __shared__ float W2s[64][129];
    __shared__ float hs[32][68];
    __shared__ float Ts[32][68];
    __shared__ float b1s[64];
    __shared__ float b2s[128];
    const int tid = threadIdx.x;
    const int row0 = blockIdx.x * 32;

    if (tid < 32) sums[row0 + tid] = 1.0f;

    for (int e = tid; e < 64 * 64; e += 256) W1s[e >> 6][e & 63] = W1[e];
    for (int e = tid; e < 64 * 128; e += 256) W2s[e >> 7][e & 127] = W2[e];
    for (int e = tid; e < 32 * 64; e += 256) hs[e >> 6][e & 63] = h[(size_t)row0 * 64 + e];
    if (tid < 64) b1s[tid] = b1[tid];
    if (tid < 128) b2s[tid] = b2[tid];
    __syncthreads();

    {
        const int c = tid & 63;
        const int r0 = (tid >> 6) * 8;
        float s[8];
        #pragma unroll
        for (int j = 0; j < 8; ++j) s[j] = b1s[c];
        #pragma unroll
        for (int k0 = 0; k0 < 64; k0 += 4) {
            const float w0 = W1s[k0 + 0][c], w1 = W1s[k0 + 1][c];
            const float w2 = W1s[k0 + 2][c], w3 = W1s[k0 + 3][c];
            #pragma unroll
            for (int j = 0; j < 8; ++j) {
                f32x4 hv = *(const f32x4*)&hs[r0 + j][k0];
                s[j] = fmaf(hv[0], w0, s[j]);
                s[j] = fmaf(hv[1], w1, s[j]);
                s[j] = fmaf(hv[2], w2, s[j]);
                s[j] = fmaf(hv[3], w3, s[j]);
            }
        }
        #pragma unroll
        for (int j = 0; j < 8; ++j) Ts[r0 + j][c] = fmaxf(s[j], 0.0f);
    }
    __syncthreads();
    {
        const int c = tid & 127;
        const int r0 = (tid >> 7) * 16;
        float s[16];
        #pragma unroll
        for (int j = 0; j < 16; ++j) s[j] = b2s[c];
        #pragma unroll
        for (int k0 = 0; k0 < 64; k0 += 4) {
            const float w0 = W2s[k0 + 0][c], w1 = W2s[k0 + 1][c];
            const float w2 = W2s[k0 + 2][c], w3 = W2s[k0 + 3][c];
            #pragma unroll
            for (int j = 0; j < 16; ++j) {
                f32x4 tv = *(const f32x4*)&Ts[r0 + j][k0];
                s[j] = fmaf(tv[0], w0, s[j]);
                s[j] = fmaf(tv[1], w1, s[j]);
                s[j] = fmaf(tv[2], w2, s[j]);
                s[j] = fmaf(tv[3], w3, s[j]);
            }
        }
        #pragma unroll
        for (int j = 0; j < 16; ++j)
            Zf[(size_t)(row0 + r0 + j) * ZD + c] = (_Float16)s[j];
    }
}

// ---------------------------------------------------------------------------
// k3: 2080 upper tiles, XCD-swizzled 1-D grid, 128x128 per block, 4 waves.
// A/B staged ONCE into padded LDS, f16 MFMA GEMM from LDS. Epilogue: LDS T
// (aliased) -> nt-writes of logits [i,j] and [j,i]; v = sigmoid(gumbel+L) as
// u8 into the full symmetric vfull matrix (transposed side via vT LDS);
// row/col sums in fp32.
// ---------------------------------------------------------------------------
#define AROW 136   // f16 per LDS row (128 + 8 pad)

__global__ __launch_bounds__(256, 2) void k3_main(
    const _Float16* __restrict__ Zf, const float* __restrict__ noise,
    float* __restrict__ logits, unsigned char* __restrict__ vfull,
    float* __restrict__ sums)
{
    int ti, tj;
    const int t = (blockIdx.x & 7) * (NUPPER / 8) + (blockIdx.x >> 3);  // XCD swizzle
    tile_decode(t, ti, tj);
    const bool diag = (ti == tj);

    __shared__ _Float16 smem[2 * 128 * AROW];   // 69632 B
    __shared__ float rs[128], cs[128];
    _Float16* As = smem;                         // [128][AROW]
    _Float16* Bs = smem + 128 * AROW;
    float (*T)[65] = (float(*)[65])smem;         // alias: 33280 B < 34816 (A region)
    unsigned char* vT = (unsigned char*)(smem + 128 * AROW);  // alias: 8 KB in B region

    const int tid = threadIdx.x;
    const int lane = tid & 63;
    const int w = tid >> 6;
    const int wr = w >> 1, wc = w & 1;
    const int fr = lane & 15;     // fragment row
    const int kg = lane >> 4;     // k-group 0..3
    const int i0 = ti * 128, j0 = tj * 128;

    // ---- stage A,B tiles into LDS (single global read of Zf per block) ----
    #pragma unroll
    for (int p = 0; p < 8; ++p) {
        const int c = tid + p * 256;            // 0..2047 chunks of 8 f16
        const int row = c >> 4, cg = (c & 15) << 3;
        *(f16x8*)&As[row * AROW + cg] = *(const f16x8*)(Zf + (size_t)(i0 + row) * ZD + cg);
        *(f16x8*)&Bs[row * AROW + cg] = *(const f16x8*)(Zf + (size_t)(j0 + row) * ZD + cg);
    }
    if (tid < 128) { rs[tid] = 0.0f; cs[tid] = 0.0f; }
    __syncthreads();

    f32x4 acc[4][4];
    #pragma unroll
    for (int mf = 0; mf < 4; ++mf)
        #pragma unroll
        for (int nf = 0; nf < 4; ++nf)
            acc[mf][nf] = (f32x4)0.0f;

    #pragma unroll
    for (int kc = 0; kc < 4; ++kc) {
        const int ko = kc * 32 + kg * 8;
        f16x8 a[4], b[4];
        #pragma unroll
        for (int mf = 0; mf < 4; ++mf) {
            a[mf] = *(const f16x8*)&As[(wr * 64 + mf * 16 + fr) * AROW + ko];
            b[mf] = *(const f16x8*)&Bs[(wc * 64 + mf * 16 + fr) * AROW + ko];
        }
        #pragma unroll
        for (int mf = 0; mf < 4; ++mf)
            #pragma unroll
            for (int nf = 0; nf < 4; ++nf)
                acc[mf][nf] = __builtin_amdgcn_mfma_f32_16x16x32_f16(a[mf], b[nf], acc[mf][nf], 0, 0, 0);
    }

    // ---- epilogue in two 64-column halves ----
    const int c4 = (tid & 15) * 4;        // local col group within half
    const int rbase = tid >> 4;           // 0..15

    #pragma unroll
    for (int half = 0; half < 2; ++half) {
        __syncthreads();   // K-loop (or prev half) done; safe to overwrite aliases
        if (wc == half) {
            #pragma unroll
            for (int mf = 0; mf < 4; ++mf)
                #pragma unroll
                for (int nf = 0; nf < 4; ++nf)
                    #pragma unroll
                    for (int r = 0; r < 4; ++r)
                        T[wr * 64 + mf * 16 + (lane >> 4) * 4 + r][nf * 16 + fr] = acc[mf][nf][r];
        }
        __syncthreads();

        f32x4 csum = (f32x4)0.0f;
        #pragma unroll
        for (int it = 0; it < 8; ++it) {
            const int r = rbase + it * 16;
            f32x4 L4 = *(const f32x4*)&T[r][c4];
            const int lc0 = half * 64 + c4;
            const size_t g = (size_t)(i0 + r) * N + j0 + lc0;
            __builtin_nontemporal_store(L4, (f32x4*)&logits[g]);
            f32x4 u4 = __builtin_nontemporal_load((const f32x4*)&noise[g]);
            float rsum = 0.0f;
            unsigned q = 0;
            #pragma unroll
            for (int e = 0; e < 4; ++e) {
                float u = u4[e];
                float eps = fmaf(-0.9998f, u, 0.9999f);   // eps in [1e-4, 1-1e-4]
                float om  = fmaf( 0.9998f, u, 0.0001f);   // 1 - eps
                float gate = __logf(eps) - __logf(om) + L4[e];
                float v = 1.0f / (1.0f + __expf(-gate));
                if (diag && r >= lc0 + e) v = 0.0f;       // strict upper
                q |= ((unsigned)(int)rintf(v * 255.0f)) << (8 * e);
                rsum += v;
                csum[e] += v;
            }
            if (!diag) {
                __builtin_nontemporal_store(q, (unsigned*)&vfull[g]);
            } else {
                // strictly-upper bytes only (disjoint from transposed writes)
                #pragma unroll
                for (int e = 0; e < 4; ++e)
                    if (r < lc0 + e) vfull[g + e] = (unsigned char)((q >> (8 * e)) & 255);
            }
            // transposed u8 into vT[c][r]
            #pragma unroll
            for (int e = 0; e < 4; ++e)
                vT[(c4 + e) * 128 + r] = (unsigned char)((q >> (8 * e)) & 255);
            atomicAdd(&rs[r], rsum);
        }
        #pragma unroll
        for (int e = 0; e < 4; ++e)
            atomicAdd(&cs[half * 64 + c4 + e], csum[e]);

        __syncthreads();   // vT complete

        // mirrors: logits [j,i] from T, vfull [j,i] from vT
        #pragma unroll
        for (int it = 0; it < 8; ++it) {
            const int idx = tid + it * 256;     // 0..2047
            const int c = idx >> 5;             // 0..63 (col within half)
            const int m4 = (idx & 31) * 4;      // row group
            const unsigned qd = *(const unsigned*)&vT[c * 128 + m4];
            if (!diag) {
                f32x4 o;
                o[0] = T[m4 + 0][c]; o[1] = T[m4 + 1][c];
                o[2] = T[m4 + 2][c]; o[3] = T[m4 + 3][c];
                __builtin_nontemporal_store(o, (f32x4*)&logits[(size_t)(j0 + half * 64 + c) * N + i0 + m4]);
                __builtin_nontemporal_store(qd, (unsigned*)&vfull[(size_t)(j0 + half * 64 + c) * N + i0 + m4]);
            } else {
                const int rr = half * 64 + c;   // local row on the mirrored side
                #pragma unroll
                for (int e = 0; e < 4; ++e)
                    if (m4 + e < rr)
                        vfull[(size_t)(i0 + rr) * N + i0 + m4 + e] = (unsigned char)((qd >> (8 * e)) & 255);
            }
        }
    }

    __syncthreads();
    if (tid < 128) {
        if (diag) {
            atomicAdd(&sums[i0 + tid], rs[tid] + cs[tid]);
        } else {
            atomicAdd(&sums[i0 + tid], rs[tid]);
            atomicAdd(&sums[j0 + tid], cs[tid]);
        }
    }
}

// ---------------------------------------------------------------------------
// k4: d = rsqrt(rowsum)
// ---------------------------------------------------------------------------
__global__ void k4_dvec(const float* __restrict__ sums, float* __restrict__ dvec)
{
    int i = blockIdx.x * 256 + threadIdx.x;
    if (i < N) dvec[i] = rsqrtf(sums[i]);
}

// ---------------------------------------------------------------------------
// k5: flat streaming normalize. Each thread/iter: read ONE u32 (4 u8,
// 256B/wave contiguous) -> write ONE f32x4 (1KB/wave contiguous). No LDS;
// dvec (32KB) is L1/L2-resident, dvec[row] wave-uniform. Diagonal inline.
// ---------------------------------------------------------------------------
__global__ __launch_bounds__(256) void k5_norm(
    const unsigned char* __restrict__ vfull, float* __restrict__ adj,
    const float* __restrict__ dvec)
{
    const unsigned CHUNKS_PER_ROW = N / 4;               // 2048
    const unsigned stride = gridDim.x * 256;
    const float inv255 = 1.0f / 255.0f;

    for (unsigned idx = blockIdx.x * 256 + threadIdx.x; idx < (unsigned)(N / 4) * N;
         idx += stride) {
        const unsigned row = idx / CHUNKS_PER_ROW;
        const unsigned col4 = (idx % CHUNKS_PER_ROW) * 4;
        const unsigned q = __builtin_nontemporal_load((const unsigned*)&vfull[(size_t)idx * 4]);
        const float sdi = dvec[row] * inv255;
        const f32x4 d4 = *(const f32x4*)&dvec[col4];
        f32x4 o;
        o[0] = (float)(q & 255)         * sdi * d4[0];
        o[1] = (float)((q >> 8) & 255)  * sdi * d4[1];
        o[2] = (float)((q >> 16) & 255) * sdi * d4[2];
        o[3] = (float)(q >> 24)         * sdi * d4[3];
        if (row - col4 < 4u) {
            const float di = dvec[row];
            o[row - col4] = di * di;
        }
        __builtin_nontemporal_store(o, (f32x4*)&adj[(size_t)idx * 4]);
    }
}

// ---------------------------------------------------------------------------
extern "C" void kernel_launch(void* const* d_in, const int* in_sizes, int n_in,
                              void* d_out, int out_size, void* d_ws, size_t ws_size,
                              hipStream_t stream)
{
    const float* h     = (const float*)d_in[0];
    const float* W1    = (const float*)d_in[1];
    const float* b1    = (const float*)d_in[2];
    const float* W2    = (const float*)d_in[3];
    const float* b2    = (const float*)d_in[4];
    const float* noise = (const float*)d_in[5];

    float* adj    = (float*)d_out;                 // output 0: adj_norm [N,N]
    float* logits = adj + (size_t)N * N;           // output 1: adj_logits [N,N]

    _Float16* Zf         = (_Float16*)d_ws;                        // 2 MiB
    unsigned char* vfull = (unsigned char*)(Zf + (size_t)N * ZD);  // [N,N] u8 = 64 MiB
    float* sums          = (float*)(vfull + (size_t)N * N);        // [N]
    float* dvec          = sums + N;                               // [N]

    k1_mlp<<<256, 256, 0, stream>>>(h, W1, b1, W2, b2, Zf, sums);
    k3_main<<<NUPPER, 256, 0, stream>>>(Zf, noise, logits, vfull, sums);
    k4_dvec<<<32, 256, 0, stream>>>(sums, dvec);
    k5_norm<<<4096, 256, 0, stream>>>(vfull, adj, dvec);
}

// Round 9
// 244.651 us; speedup vs baseline: 2.8046x; 1.0892x over previous
//
#include <hip/hip_runtime.h>
#include <hip/hip_bf16.h>
#include <math.h>

#define N 8192
#define ZD 128
#define NTILE 64            // N / 128
#define NUPPER 2080         // NTILE*(NTILE+1)/2  (= 8 * 260, divisible by 8)

typedef __attribute__((ext_vector_type(8))) _Float16 f16x8;
typedef __attribute__((ext_vector_type(4))) float f32x4;

__device__ __forceinline__ int tri_cum(int ti) {   // tiles before row ti
    return (ti * (2 * NTILE + 1 - ti)) / 2;        // ti*(129-ti)/2
}

__device__ __forceinline__ void tile_decode(int t, int& ti, int& tj) {
    int est = (int)((129.0f - sqrtf(16641.0f - 8.0f * (float)t)) * 0.5f);
    if (est < 0) est = 0;
    while (tri_cum(est) > t) --est;
    while (tri_cum(est + 1) <= t) ++est;
    ti = est;
    tj = est + (t - tri_cum(est));
}

// ---------------------------------------------------------------------------
// k1: Z = relu(h @ W1 + b1) @ W2 + b2 (fp32 math), stored as f16.
// Also initializes sums[i] = 1.0 (the fill_diagonal(1) contribution).
// ---------------------------------------------------------------------------
__global__ __launch_bounds__(256) void k1_mlp(
    const float* __restrict__ h, const float* __restrict__ W1,
    const float* __restrict__ b1, const float* __restrict__ W2,
    const float* __restrict__ b2, _Float16* __restrict__ Zf,
    float* __restrict__ sums)
{
    __shared__ float W1s[64][65];
    __shared__ float W2s[64][129];
    __shared__ float hs[32][68];
    __shared__ float Ts[32][68];
    __shared__ float b1s[64];
    __shared__ float b2s[128];
    const int tid = threadIdx.x;
    const int row0 = blockIdx.x * 32;

    if (tid < 32) sums[row0 + tid] = 1.0f;

    for (int e = tid; e < 64 * 64; e += 256) W1s[e >> 6][e & 63] = W1[e];
    for (int e = tid; e < 64 * 128; e += 256) W2s[e >> 7][e & 127] = W2[e];
    for (int e = tid; e < 32 * 64; e += 256) hs[e >> 6][e & 63] = h[(size_t)row0 * 64 + e];
    if (tid < 64) b1s[tid] = b1[tid];
    if (tid < 128) b2s[tid] = b2[tid];
    __syncthreads();

    {
        const int c = tid & 63;
        const int r0 = (tid >> 6) * 8;
        float s[8];
        #pragma unroll
        for (int j = 0; j < 8; ++j) s[j] = b1s[c];
        #pragma unroll
        for (int k0 = 0; k0 < 64; k0 += 4) {
            const float w0 = W1s[k0 + 0][c], w1 = W1s[k0 + 1][c];
            const float w2 = W1s[k0 + 2][c], w3 = W1s[k0 + 3][c];
            #pragma unroll
            for (int j = 0; j < 8; ++j) {
                f32x4 hv = *(const f32x4*)&hs[r0 + j][k0];
                s[j] = fmaf(hv[0], w0, s[j]);
                s[j] = fmaf(hv[1], w1, s[j]);
                s[j] = fmaf(hv[2], w2, s[j]);
                s[j] = fmaf(hv[3], w3, s[j]);
            }
        }
        #pragma unroll
        for (int j = 0; j < 8; ++j) Ts[r0 + j][c] = fmaxf(s[j], 0.0f);
    }
    __syncthreads();
    {
        const int c = tid & 127;
        const int r0 = (tid >> 7) * 16;
        float s[16];
        #pragma unroll
        for (int j = 0; j < 16; ++j) s[j] = b2s[c];
        #pragma unroll
        for (int k0 = 0; k0 < 64; k0 += 4) {
            const float w0 = W2s[k0 + 0][c], w1 = W2s[k0 + 1][c];
            const float w2 = W2s[k0 + 2][c], w3 = W2s[k0 + 3][c];
            #pragma unroll
            for (int j = 0; j < 16; ++j) {
                f32x4 tv = *(const f32x4*)&Ts[r0 + j][k0];
                s[j] = fmaf(tv[0], w0, s[j]);
                s[j] = fmaf(tv[1], w1, s[j]);
                s[j] = fmaf(tv[2], w2, s[j]);
                s[j] = fmaf(tv[3], w3, s[j]);
            }
        }
        #pragma unroll
        for (int j = 0; j < 16; ++j)
            Zf[(size_t)(row0 + r0 + j) * ZD + c] = (_Float16)s[j];
    }
}

// ---------------------------------------------------------------------------
// k3: 2080 upper tiles, XCD-swizzled 1-D grid, 128x128 per block, 4 waves,
// 3 blocks/CU. f16 MFMA GEMM, fragments loaded DIRECT from global (Zf = 2 MiB
// stays L2-resident; all big streams are nontemporal). Epilogue: T in LDS ->
// nt-writes of logits [i,j] and [j,i]; v = sigmoid(gumbel+L) as u8 into the
// full symmetric vfull (transposed side via padded vT LDS); row/col sums.
// ---------------------------------------------------------------------------
__global__ __launch_bounds__(256, 3) void k3_main(
    const _Float16* __restrict__ Zf, const float* __restrict__ noise,
    float* __restrict__ logits, unsigned char* __restrict__ vfull,
    float* __restrict__ sums)
{
    int ti, tj;
    const int t = (blockIdx.x & 7) * (NUPPER / 8) + (blockIdx.x >> 3);  // XCD swizzle
    tile_decode(t, ti, tj);
    const bool diag = (ti == tj);

    __shared__ float T[128][65];                 // 33280 B
    __shared__ unsigned char vT[64 * 132];       // 8448 B (132-stride: conflict-free)
    __shared__ float rs[128], cs[128];

    const int tid = threadIdx.x;
    const int lane = tid & 63;
    const int w = tid >> 6;
    const int wr = w >> 1, wc = w & 1;
    const int fr = lane & 15;     // fragment row
    const int kg = lane >> 4;     // k-group 0..3
    const int i0 = ti * 128, j0 = tj * 128;

    if (tid < 128) { rs[tid] = 0.0f; cs[tid] = 0.0f; }

    const _Float16* Ap = Zf + (size_t)(i0 + wr * 64) * ZD;
    const _Float16* Bp = Zf + (size_t)(j0 + wc * 64) * ZD;

    f32x4 acc[4][4];
    #pragma unroll
    for (int mf = 0; mf < 4; ++mf)
        #pragma unroll
        for (int nf = 0; nf < 4; ++nf)
            acc[mf][nf] = (f32x4)0.0f;

    #pragma unroll
    for (int kc = 0; kc < 4; ++kc) {
        const int ko = kc * 32 + kg * 8;
        f16x8 a[4], b[4];
        #pragma unroll
        for (int mf = 0; mf < 4; ++mf) {
            size_t off = (size_t)(mf * 16 + fr) * ZD + ko;
            a[mf] = *(const f16x8*)(Ap + off);
            b[mf] = *(const f16x8*)(Bp + off);
        }
        #pragma unroll
        for (int mf = 0; mf < 4; ++mf)
            #pragma unroll
            for (int nf = 0; nf < 4; ++nf)
                acc[mf][nf] = __builtin_amdgcn_mfma_f32_16x16x32_f16(a[mf], b[nf], acc[mf][nf], 0, 0, 0);
    }

    // ---- epilogue in two 64-column halves ----
    const int c4 = (tid & 15) * 4;        // local col group within half
    const int rbase = tid >> 4;           // 0..15

    #pragma unroll
    for (int half = 0; half < 2; ++half) {
        __syncthreads();   // prev half's readers done / rs,cs init visible
        if (wc == half) {
            #pragma unroll
            for (int mf = 0; mf < 4; ++mf)
                #pragma unroll
                for (int nf = 0; nf < 4; ++nf)
                    #pragma unroll
                    for (int r = 0; r < 4; ++r)
                        T[wr * 64 + mf * 16 + (lane >> 4) * 4 + r][nf * 16 + fr] = acc[mf][nf][r];
        }
        __syncthreads();

        f32x4 csum = (f32x4)0.0f;
        #pragma unroll
        for (int it = 0; it < 8; ++it) {
            const int r = rbase + it * 16;
            f32x4 L4 = *(const f32x4*)&T[r][c4];
            const int lc0 = half * 64 + c4;
            const size_t g = (size_t)(i0 + r) * N + j0 + lc0;
            __builtin_nontemporal_store(L4, (f32x4*)&logits[g]);
            f32x4 u4 = __builtin_nontemporal_load((const f32x4*)&noise[g]);
            float rsum = 0.0f;
            unsigned q = 0;
            #pragma unroll
            for (int e = 0; e < 4; ++e) {
                float u = u4[e];
                float eps = fmaf(-0.9998f, u, 0.9999f);   // eps in [1e-4, 1-1e-4]
                float om  = fmaf( 0.9998f, u, 0.0001f);   // 1 - eps
                float gate = __logf(eps) - __logf(om) + L4[e];
                float v = 1.0f / (1.0f + __expf(-gate));
                if (diag && r >= lc0 + e) v = 0.0f;       // strict upper
                q |= ((unsigned)(int)rintf(v * 255.0f)) << (8 * e);
                rsum += v;
                csum[e] += v;
            }
            if (!diag) {
                __builtin_nontemporal_store(q, (unsigned*)&vfull[g]);
            } else {
                // strictly-upper bytes only (disjoint from mirrored writes)
                #pragma unroll
                for (int e = 0; e < 4; ++e)
                    if (r < lc0 + e) vfull[g + e] = (unsigned char)((q >> (8 * e)) & 255);
            }
            // transposed u8 into vT[c][r], padded stride 132
            #pragma unroll
            for (int e = 0; e < 4; ++e)
                vT[(c4 + e) * 132 + r] = (unsigned char)((q >> (8 * e)) & 255);
            atomicAdd(&rs[r], rsum);
        }
        #pragma unroll
        for (int e = 0; e < 4; ++e)
            atomicAdd(&cs[half * 64 + c4 + e], csum[e]);

        __syncthreads();   // vT complete

        // mirrors: logits [j,i] from T, vfull [j,i] from vT
        #pragma unroll
        for (int it = 0; it < 8; ++it) {
            const int idx = tid + it * 256;     // 0..2047
            const int c = idx >> 5;             // 0..63 (col within half)
            const int m4 = (idx & 31) * 4;      // row group
            const unsigned qd = *(const unsigned*)&vT[c * 132 + m4];
            if (!diag) {
                f32x4 o;
                o[0] = T[m4 + 0][c]; o[1] = T[m4 + 1][c];
                o[2] = T[m4 + 2][c]; o[3] = T[m4 + 3][c];
                __builtin_nontemporal_store(o, (f32x4*)&logits[(size_t)(j0 + half * 64 + c) * N + i0 + m4]);
                __builtin_nontemporal_store(qd, (unsigned*)&vfull[(size_t)(j0 + half * 64 + c) * N + i0 + m4]);
            } else {
                const int rr = half * 64 + c;   // local row on the mirrored side
                #pragma unroll
                for (int e = 0; e < 4; ++e)
                    if (m4 + e < rr)
                        vfull[(size_t)(i0 + rr) * N + i0 + m4 + e] = (unsigned char)((qd >> (8 * e)) & 255);
            }
        }
    }

    __syncthreads();
    if (tid < 128) {
        if (diag) {
            atomicAdd(&sums[i0 + tid], rs[tid] + cs[tid]);
        } else {
            atomicAdd(&sums[i0 + tid], rs[tid]);
            atomicAdd(&sums[j0 + tid], cs[tid]);
        }
    }
}

// ---------------------------------------------------------------------------
// k4: d = rsqrt(rowsum)
// ---------------------------------------------------------------------------
__global__ void k4_dvec(const float* __restrict__ sums, float* __restrict__ dvec)
{
    int i = blockIdx.x * 256 + threadIdx.x;
    if (i < N) dvec[i] = rsqrtf(sums[i]);
}

// ---------------------------------------------------------------------------
// k5: flat streaming normalize. Each thread/iter: read ONE u32 (4 u8,
// 256B/wave contiguous) -> write ONE f32x4 (1KB/wave contiguous). No LDS;
// dvec (32KB) is L1/L2-resident, dvec[row] wave-uniform. Diagonal inline.
// ---------------------------------------------------------------------------
__global__ __launch_bounds__(256) void k5_norm(
    const unsigned char* __restrict__ vfull, float* __restrict__ adj,
    const float* __restrict__ dvec)
{
    const unsigned CHUNKS_PER_ROW = N / 4;               // 2048
    const unsigned stride = gridDim.x * 256;
    const float inv255 = 1.0f / 255.0f;

    for (unsigned idx = blockIdx.x * 256 + threadIdx.x; idx < (unsigned)(N / 4) * N;
         idx += stride) {
        const unsigned row = idx / CHUNKS_PER_ROW;
        const unsigned col4 = (idx % CHUNKS_PER_ROW) * 4;
        const unsigned q = __builtin_nontemporal_load((const unsigned*)&vfull[(size_t)idx * 4]);
        const float sdi = dvec[row] * inv255;
        const f32x4 d4 = *(const f32x4*)&dvec[col4];
        f32x4 o;
        o[0] = (float)(q & 255)         * sdi * d4[0];
        o[1] = (float)((q >> 8) & 255)  * sdi * d4[1];
        o[2] = (float)((q >> 16) & 255) * sdi * d4[2];
        o[3] = (float)(q >> 24)         * sdi * d4[3];
        if (row - col4 < 4u) {
            const float di = dvec[row];
            o[row - col4] = di * di;
        }
        __builtin_nontemporal_store(o, (f32x4*)&adj[(size_t)idx * 4]);
    }
}

// ---------------------------------------------------------------------------
extern "C" void kernel_launch(void* const* d_in, const int* in_sizes, int n_in,
                              void* d_out, int out_size, void* d_ws, size_t ws_size,
                              hipStream_t stream)
{
    const float* h     = (const float*)d_in[0];
    const float* W1    = (const float*)d_in[1];
    const float* b1    = (const float*)d_in[2];
    const float* W2    = (const float*)d_in[3];
    const float* b2    = (const float*)d_in[4];
    const float* noise = (const float*)d_in[5];

    float* adj    = (float*)d_out;                 // output 0: adj_norm [N,N]
    float* logits = adj + (size_t)N * N;           // output 1: adj_logits [N,N]

    _Float16* Zf         = (_Float16*)d_ws;                        // 2 MiB
    unsigned char* vfull = (unsigned char*)(Zf + (size_t)N * ZD);  // [N,N] u8 = 64 MiB
    float* sums          = (float*)(vfull + (size_t)N * N);        // [N]
    float* dvec          = sums + N;                               // [N]

    k1_mlp<<<256, 256, 0, stream>>>(h, W1, b1, W2, b2, Zf, sums);
    k3_main<<<NUPPER, 256, 0, stream>>>(Zf, noise, logits, vfull, sums);
    k4_dvec<<<32, 256, 0, stream>>>(sums, dvec);
    k5_norm<<<4096, 256, 0, stream>>>(vfull, adj, dvec);
}